// Round 10
// baseline (266.825 us; speedup 1.0000x reference)
//
#include <hip/hip_runtime.h>

constexpr int kB  = 16;
constexpr int kLM = 1024;
constexpr int kLX = 1024;
constexpr int kD  = 768;

using short8 = __attribute__((ext_vector_type(8))) short;
using f32x4  = __attribute__((ext_vector_type(4))) float;

__device__ __forceinline__ unsigned short f2bf(float f) {
    unsigned u = __float_as_uint(f);
    u = (u + 0x7FFF + ((u >> 16) & 1)) >> 16;   // RNE
    return (unsigned short)u;
}
__device__ __forceinline__ float bf2f(unsigned short h) {
    return __uint_as_float(((unsigned)h) << 16);
}

// async 16B global->LDS copy; dst must be wave-uniform base + lane*16.
__device__ __forceinline__ void gl_lds16(const unsigned short* g, unsigned short* l) {
    auto gp = (const __attribute__((address_space(1))) unsigned int*)g;
    auto lp = (__attribute__((address_space(3))) unsigned int*)l;
    __builtin_amdgcn_global_load_lds(gp, lp, 16, 0, 0);
}

// inverse XOR swizzle: LDS chunk index -> global (row, kseg) element offset
__device__ __forceinline__ size_t chunk_off(int c, int K) {
    int sr = c >> 3, s = c & 7;
    int tt = s ^ (sr & 7);
    int r  = sr * 2 + (tt >> 2);
    int q  = tt & 3;
    return (size_t)r * K + q * 8;
}

// ---------------------------------------------------------------------------
// Prep (one dispatch, item-range): x transpose+cvt, main cvt, W cvt, zero out.
// ---------------------------------------------------------------------------
__global__ __launch_bounds__(256) void prep_kernel(
    const float* __restrict__ x, unsigned short* __restrict__ xT,
    const float* __restrict__ mainp, unsigned short* __restrict__ mainb,
    const float* __restrict__ W, unsigned short* __restrict__ Wb,
    float* __restrict__ out) {
    __shared__ float tile[64][65];
    const int item = blockIdx.x;
    const int t = threadIdx.x;
    if (item < 3072) {
        const int b  = item / 192, rem = item % 192;
        const int l0 = (rem / 12) * 64, d0 = (rem % 12) * 64;
        const int tx = t & 15, ty = t >> 4;
        const float* xb = x + ((size_t)b * kLX + l0) * kD + d0;
#pragma unroll
        for (int p = 0; p < 4; ++p) {
            int r = p * 16 + ty;
            float4 v = *(const float4*)(xb + (size_t)r * kD + tx * 4);
            *(float4*)&tile[r][tx * 4] = v;
        }
        __syncthreads();
        unsigned short* xTb = xT + ((size_t)b * kD + d0) * kLX + l0;
#pragma unroll
        for (int p = 0; p < 4; ++p) {
            int dr = p * 16 + ty;
            ushort4 o;
            o.x = f2bf(tile[tx * 4 + 0][dr]);
            o.y = f2bf(tile[tx * 4 + 1][dr]);
            o.z = f2bf(tile[tx * 4 + 2][dr]);
            o.w = f2bf(tile[tx * 4 + 3][dr]);
            *(ushort4*)(xTb + (size_t)dr * kLX + tx * 4) = o;
        }
    } else if (item < 6144) {
        const size_t base = (size_t)(item - 3072) * 1024;
        const float4* src = (const float4*)mainp + base;
        ushort4* dst = (ushort4*)mainb + base;
#pragma unroll
        for (int u = 0; u < 4; ++u) {
            float4 v = src[t + u * 256];
            ushort4 o;
            o.x = f2bf(v.x); o.y = f2bf(v.y); o.z = f2bf(v.z); o.w = f2bf(v.w);
            dst[t + u * 256] = o;
        }
    } else if (item < 6288) {
        const size_t base = (size_t)(item - 6144) * 1024;
        const float4* src = (const float4*)W + base;
        ushort4* dst = (ushort4*)Wb + base;
#pragma unroll
        for (int u = 0; u < 4; ++u) {
            float4 v = src[t + u * 256];
            ushort4 o;
            o.x = f2bf(v.x); o.y = f2bf(v.y); o.z = f2bf(v.z); o.w = f2bf(v.w);
            dst[t + u * 256] = o;
        }
    } else {
        const size_t base = (size_t)(item - 6288) * 1024;
        float4* dst = (float4*)out + base;
        const float4 z4 = {0.f, 0.f, 0.f, 0.f};
#pragma unroll
        for (int u = 0; u < 4; ++u) dst[t + u * 256] = z4;
    }
}

// ---------------------------------------------------------------------------
// NT bf16 MFMA GEMM, 128x64 tile, BK=32, 256 thr, 2x4 MFMA/wave.
// TRIPLE-buffered 2-phase pipeline with RAW s_barrier + explicit vmcnt:
//   iter kt: s_waitcnt vmcnt(3)  (drains tile kt; tile kt+1 stays in flight)
//            s_barrier           (raw — no compiler vmcnt(0) drain!)
//            issue tile kt+2 into buf[(kt+2)%3]  (= buffer consumed at kt-1;
//              safe: every wave's kt-1 MFMAs lgkm-drained before this barrier)
//            ds_read + MFMA tile kt
// Loads get ~2 compute phases of latency slack instead of 1, and the
// prefetch queue is never drained by the barrier (the m97-structure stall).
// ---------------------------------------------------------------------------
__global__ __launch_bounds__(256) void gemm_nt_kernel(
    const unsigned short* __restrict__ A, const unsigned short* __restrict__ B,
    unsigned short* __restrict__ C, int M, int N, int K,
    long sA, long sB, long sC) {
    __shared__ unsigned short Asm[3][128 * 32];   // 8 KB each
    __shared__ unsigned short Bsm[3][64 * 32];    // 4 KB each
    const int b  = blockIdx.z;
    const int i0 = blockIdx.x * 128;
    const int j0 = blockIdx.y * 64;
    const int t    = threadIdx.x;
    const int wave = t >> 6, lane = t & 63;
    const int quad = lane >> 4, l15 = lane & 15;

    const unsigned short* Ab = A + (size_t)b * sA + (size_t)i0 * K;
    const unsigned short* Bb = B + (size_t)b * sB + (size_t)j0 * K;

    const int cA0 = t, cA1 = t + 256, cB = t;    // A: 512 chunks, B: 256 chunks
    const size_t offA0 = chunk_off(cA0, K);
    const size_t offA1 = chunk_off(cA1, K);
    const size_t offB  = chunk_off(cB, K);

    const int sfr  = ((l15 & 1) * 4 + quad) ^ ((l15 >> 1) & 7);
    const int aOff = wave * 1024 + (l15 >> 1) * 64 + sfr * 8;
    const int bOff = (l15 >> 1) * 64 + sfr * 8;

    f32x4 acc[2][4];
    const f32x4 z = {0.f, 0.f, 0.f, 0.f};
#pragma unroll
    for (int i = 0; i < 2; ++i)
#pragma unroll
        for (int j = 0; j < 4; ++j) acc[i][j] = z;

    auto issue = [&](int kt, int bi) {
        const size_t k = (size_t)kt << 5;
        gl_lds16(Ab + offA0 + k, Asm[bi] + cA0 * 8);
        gl_lds16(Ab + offA1 + k, Asm[bi] + cA1 * 8);
        gl_lds16(Bb + offB + k,  Bsm[bi] + cB * 8);
    };

    const int T = K >> 5;
    // prologue: tiles 0,1 -> bufs 0,1
    issue(0, 0);
    issue(1, 1);

    int bc = 0;   // buf of current tile kt
    for (int kt = 0; kt < T; ++kt) {
        if (kt + 1 < T) {
            asm volatile("s_waitcnt vmcnt(3)" ::: "memory");
        } else {
            asm volatile("s_waitcnt vmcnt(0)" ::: "memory");
        }
        asm volatile("s_barrier" ::: "memory");
        if (kt + 2 < T) {
            int bi = bc + 2; if (bi >= 3) bi -= 3;
            issue(kt + 2, bi);
        }
        const unsigned short* aP = Asm[bc] + aOff;
        const unsigned short* bP = Bsm[bc] + bOff;
        short8 af[2], bg[4];
#pragma unroll
        for (int i = 0; i < 2; ++i) af[i] = *(const short8*)(aP + i * 512);
#pragma unroll
        for (int j = 0; j < 4; ++j) bg[j] = *(const short8*)(bP + j * 512);
#pragma unroll
        for (int i = 0; i < 2; ++i)
#pragma unroll
            for (int j = 0; j < 4; ++j)
                acc[i][j] = __builtin_amdgcn_mfma_f32_16x16x32_bf16(
                    af[i], bg[j], acc[i][j], 0, 0, 0);
        ++bc; if (bc == 3) bc = 0;
    }

    // C/D layout: col = lane&15, row = quad*4 + reg  [m89/m91 verified]
    unsigned short* Cb = C + (size_t)b * sC + (size_t)(i0 + wave * 32) * N + j0;
#pragma unroll
    for (int i = 0; i < 2; ++i)
#pragma unroll
        for (int j = 0; j < 4; ++j)
#pragma unroll
            for (int r = 0; r < 4; ++r)
                Cb[(size_t)(i * 16 + quad * 4 + r) * N + j * 16 + l15] =
                    f2bf(acc[i][j][r]);
}

// ---------------------------------------------------------------------------
// Fused beta + pooled. Grid (64,16). Cross-wave LDS pre-reduction.
// ---------------------------------------------------------------------------
__global__ __launch_bounds__(256) void pool_kernel(
    const float* __restrict__ mainp, const unsigned short* __restrict__ Aout,
    const float* __restrict__ w, float* __restrict__ out) {
    __shared__ float red[4][24][64];   // 24 KB
    const int b     = blockIdx.y;
    const int chunk = blockIdx.x;           // 64 chunks of 16 rows
    const int t     = threadIdx.x;
    const int wave  = t >> 6, lane = t & 63;
    float w1[12], w2[12], ps[12], pm[12];
#pragma unroll
    for (int s = 0; s < 12; ++s) {
        w1[s] = w[s * 64 + lane];
        w2[s] = w[kD + s * 64 + lane];
        ps[s] = 0.f; pm[s] = 0.f;
    }
#pragma unroll
    for (int rr = 0; rr < 4; ++rr) {
        const int row = chunk * 16 + rr * 4 + wave;
        const float* mr = mainp + ((size_t)b * kLM + row) * kD;
        const unsigned short* ar = Aout + ((size_t)b * kLM + row) * kD;
        float sv[12], mv[12], acc = 0.f;
#pragma unroll
        for (int s = 0; s < 12; ++s) {
            float m_ = mr[s * 64 + lane];
            float a_ = bf2f(ar[s * 64 + lane]);
            sv[s] = m_ - a_;
            mv[s] = m_ * a_;
            acc += sv[s] * w1[s] + mv[s] * w2[s];
        }
#pragma unroll
        for (int off = 32; off; off >>= 1) acc += __shfl_xor(acc, off);
#pragma unroll
        for (int s = 0; s < 12; ++s) { ps[s] += acc * sv[s]; pm[s] += acc * mv[s]; }
    }
#pragma unroll
    for (int s = 0; s < 12; ++s) {
        red[wave][s][lane]      = ps[s];
        red[wave][12 + s][lane] = pm[s];
    }
    __syncthreads();
    float* ob = out + (size_t)b * 2 * kD;
    for (int v = t; v < 24 * 64; v += 256) {
        const int sl = v >> 6, ln = v & 63;
        const float sum = red[0][sl][ln] + red[1][sl][ln] +
                          red[2][sl][ln] + red[3][sl][ln];
        const int d = (sl < 12) ? sl * 64 + ln : kD + (sl - 12) * 64 + ln;
        atomicAdd(&ob[d], sum);
    }
}

extern "C" void kernel_launch(void* const* d_in, const int* in_sizes, int n_in,
                              void* d_out, int out_size, void* d_ws, size_t ws_size,
                              hipStream_t stream) {
    const float* mainp = (const float*)d_in[0];  // (B, LM, D)
    const float* x     = (const float*)d_in[1];  // (B, LX, D)
    const float* W     = (const float*)d_in[2];  // (D, D)
    const float* w     = (const float*)d_in[3];  // (2D, 1)
    float* out = (float*)d_out;                  // (B, 2D)

    char* p = (char*)d_ws;
    unsigned short* xT    = (unsigned short*)p; p += (size_t)kB * kD * kLX * 2;
    unsigned short* mainb = (unsigned short*)p; p += (size_t)kB * kLM * kD * 2;
    unsigned short* Wb    = (unsigned short*)p; p += (size_t)kD * kD * 2;
    unsigned short* G     = (unsigned short*)p; p += (size_t)kB * kD * kD * 2;
    unsigned short* Mt    = (unsigned short*)p; p += (size_t)kB * kD * kD * 2;
    unsigned short* Ao    = (unsigned short*)p; p += (size_t)kB * kLM * kD * 2;

    prep_kernel<<<6294, 256, 0, stream>>>(x, xT, mainp, mainb, W, Wb, out);

    // G[b] = xT[b] @ xT[b]^T     grid 1152 blocks
    gemm_nt_kernel<<<dim3(kD / 128, kD / 64, kB), 256, 0, stream>>>(
        xT, xT, G, kD, kD, kLX, (long)kD * kLX, (long)kD * kLX, (long)kD * kD);
    // Mt[b] = G[b] @ W^T         grid 1152 blocks
    gemm_nt_kernel<<<dim3(kD / 128, kD / 64, kB), 256, 0, stream>>>(
        G, Wb, Mt, kD, kD, kD, (long)kD * kD, 0L, (long)kD * kD);
    // Ao[b] = mainb[b] @ Mt[b]^T grid 1536 blocks
    gemm_nt_kernel<<<dim3(kLM / 128, kD / 64, kB), 256, 0, stream>>>(
        mainb, Mt, Ao, kLM, kD, kD, (long)kLM * kD, (long)kD * kD, (long)kLM * kD);

    pool_kernel<<<dim3(kLM / 16, kB), 256, 0, stream>>>(mainp, Ao, w, out);
}